// Round 5
// baseline (8831.227 us; speedup 1.0000x reference)
//
#include <hip/hip_runtime.h>
#include <cstdint>
#include <cstddef>

// Problem constants
#define Bb   128
#define Tt   500
#define INn  306
#define Hh   512

typedef short bf16x8 __attribute__((ext_vector_type(8)));
typedef float f32x4  __attribute__((ext_vector_type(4)));
typedef unsigned short u16t;

union F8 { bf16x8 v; uint4 q; unsigned u[4]; u16t s[8]; };

// ---- ws layout (u16 element offsets) ----
#define W0H   0u          // Whh0 hi   [512][512]
#define W0L   262144u     // Whh0 lo
#define WI0H  524288u     // Wih0 hi   [512][320]  (K padded 306->320 with zeros)
#define WI0L  688128u     // Wih0 lo
#define WI1H  851968u     // Wih1 hi   [512][512]
#define WI1L  1114112u
#define WH1H  1376256u    // Whh1 hi   [512][512]
#define WH1L  1638400u
#define H0HI  1900544u    // h0 hi     [2 slots][128][512]
#define H0LO  2031616u
#define H1HI  2162688u
#define H1LO  2293760u
#define WCONV_N 950272u   // weight elements (= 3712*256)
#define HZ_N    524288u   // h-state u16 elements to zero (= 2048*256)

__device__ __forceinline__ float bf2f(u16t h) {
  unsigned u = ((unsigned)h) << 16;
  return __builtin_bit_cast(float, u);
}
__device__ __forceinline__ u16t f2bf(float f) {
  unsigned u = __builtin_bit_cast(unsigned, f);
  unsigned r = u + 0x7fffu + ((u >> 16) & 1u);   // RNE (finite inputs only)
  return (u16t)(r >> 16);
}
// hi+lo double-bf16 split, RNE (weights / h epilogue)
__device__ __forceinline__ void splitRNE(float v, u16t& hi, u16t& lo) {
  hi = f2bf(v);
  lo = f2bf(v - bf2f(hi));
}
// truncation split (per-step x conversion; pair residual ~2^-17 rel)
__device__ __forceinline__ void splitTR(float v, u16t& hi, u16t& lo) {
  unsigned u = __builtin_bit_cast(unsigned, v);
  hi = (u16t)(u >> 16);
  float hf = __builtin_bit_cast(float, u & 0xFFFF0000u);
  lo = (u16t)(__builtin_bit_cast(unsigned, v - hf) >> 16);
}
__device__ __forceinline__ f32x4 MF(const F8& a, const F8& b, f32x4 c) {
  return __builtin_amdgcn_mfma_f32_16x16x32_bf16(a.v, b.v, c, 0, 0, 0);
}

// ---- Pre-pass: split all weights into bf16 hi/lo arrays in ws + zero h ----
// grid = 5760 * 256 covers 950,272 weight elems + 524,288 h elems exactly.
__global__ __launch_bounds__(256) void wconv(
    const float* __restrict__ Whh0, const float* __restrict__ Wih0,
    const float* __restrict__ Wih1, const float* __restrict__ Whh1,
    u16t* __restrict__ ws) {
  int i = blockIdx.x * 256 + threadIdx.x;
  if (i < 262144) {                       // Whh0 [512][512]
    u16t h, l; splitRNE(Whh0[i], h, l);
    ws[W0H + i] = h; ws[W0L + i] = l; return;
  }
  i -= 262144;
  if (i < 163840) {                       // Wih0 [512][306] -> padded [512][320]
    int j = i / 320, k = i - j * 320;
    float v = (k < INn) ? Wih0[j * INn + k] : 0.f;
    u16t h, l; splitRNE(v, h, l);
    ws[WI0H + i] = h; ws[WI0L + i] = l; return;
  }
  i -= 163840;
  if (i < 262144) {                       // Wih1 [512][512]
    u16t h, l; splitRNE(Wih1[i], h, l);
    ws[WI1H + i] = h; ws[WI1L + i] = l; return;
  }
  i -= 262144;
  if (i < 262144) {                       // Whh1 [512][512]
    u16t h, l; splitRNE(Whh1[i], h, l);
    ws[WH1H + i] = h; ws[WH1L + i] = l; return;
  }
  i -= 262144;                            // zero h state (ws poisoned 0xAA)
  ws[H0HI + i] = 0;
}

// ---- One time step: WGs 0..63 do L0 step t; WGs 64..127 do L1 step t-1 ----
// Parity slots: h0[t] -> slot t&1; h1[t1] -> slot t1&1. No intra-launch hazards;
// inter-launch ordering/visibility comes from stream kernel boundaries.
__global__ __launch_bounds__(256) void rnn_step(
    const float* __restrict__ x,
    const float* __restrict__ bih0, const float* __restrict__ bhh0,
    const float* __restrict__ bih1, const float* __restrict__ bhh1,
    u16t* __restrict__ ws, int t) {
  const int wg   = blockIdx.x;
  const int tid  = threadIdx.x;
  const int lane = tid & 63;
  const int wave = tid >> 6;
  const int l15  = lane & 15;
  const int quad = lane >> 4;

  const bool isL0 = (wg < 64);
  if (isL0 && t >= Tt) return;            // t=500: L0 idle
  if (!isL0 && t < 1) return;             // t=0:   L1 idle

  const int id    = wg & 63;
  const int Mb    = (id >> 3) * 16;           // 8 batch-row slices
  const int Jb    = (id & 7) * 64;            // 8 col slices
  const int jn    = Jb + wave * 16 + l15;     // output col / B-row
  const int rowA  = Mb + l15;                 // A row
  const int mOutB = Mb + quad * 4;            // C/D row base (quad*4 + r)
  const int koff  = quad * 8;                 // A/B k-offset within 32-chunk

  if (isL0) {
    // Layer 0: h0[t] = tanh(x_t Wih0^T + h0[t-1] Whh0^T + b)
    const float bv = bih0[jn] + bhh0[jn];
    f32x4 ac0 = {bv, bv, bv, bv};
    f32x4 ac1 = {0.f, 0.f, 0.f, 0.f};
    f32x4 ac2 = {0.f, 0.f, 0.f, 0.f};

    // x part: K = 306 padded to 320
    {
      const float* xr = x + ((size_t)rowA * Tt + t) * INn;
#pragma unroll
      for (int kc = 0; kc < 10; ++kc) {
        const int kb = kc * 32 + koff;
        F8 xh, xl;
        if (kc < 9) {
          const float2* p = (const float2*)(xr + kb);   // 8B-aligned
#pragma unroll
          for (int h2 = 0; h2 < 4; ++h2) {
            float2 w = p[h2];
            splitTR(w.x, xh.s[2 * h2],     xl.s[2 * h2]);
            splitTR(w.y, xh.s[2 * h2 + 1], xl.s[2 * h2 + 1]);
          }
        } else {
#pragma unroll
          for (int e = 0; e < 8; ++e) {
            float v = (kb + e < INn) ? xr[kb + e] : 0.f;
            splitTR(v, xh.s[e], xl.s[e]);
          }
        }
        F8 bh, bl;
        bh.q = *(const uint4*)(ws + WI0H + (size_t)jn * 320 + kb);
        bl.q = *(const uint4*)(ws + WI0L + (size_t)jn * 320 + kb);
        ac0 = MF(xh, bh, ac0);
        ac1 = MF(xh, bl, ac1);
        ac2 = MF(xl, bh, ac2);
      }
    }
    // h part: h0[t-1] in slot (t+1)&1
    {
      const int ps = (t + 1) & 1;
      const u16t* phi = ws + H0HI + (size_t)ps * 65536 + (size_t)rowA * Hh + koff;
      const u16t* plo = ws + H0LO + (size_t)ps * 65536 + (size_t)rowA * Hh + koff;
#pragma unroll
      for (int kc = 0; kc < 16; ++kc) {
        F8 ah, al, bh, bl;
        ah.q = *(const uint4*)(phi + kc * 32);
        al.q = *(const uint4*)(plo + kc * 32);
        bh.q = *(const uint4*)(ws + W0H + (size_t)jn * Hh + kc * 32 + koff);
        bl.q = *(const uint4*)(ws + W0L + (size_t)jn * Hh + kc * 32 + koff);
        ac0 = MF(ah, bh, ac0);
        ac1 = MF(ah, bl, ac1);
        ac2 = MF(al, bh, ac2);
      }
    }
    // epilogue -> h0 slot t&1
    u16t* shi = ws + H0HI + (size_t)(t & 1) * 65536;
    u16t* slo = ws + H0LO + (size_t)(t & 1) * 65536;
#pragma unroll
    for (int r = 0; r < 4; ++r) {
      const float v = tanhf(ac0[r] + ac1[r] + ac2[r]);
      u16t hb, lb; splitRNE(v, hb, lb);
      const size_t m = (size_t)(mOutB + r) * Hh;
      shi[m + jn] = hb; slo[m + jn] = lb;
    }
  } else {
    // Layer 1: t1 = t-1; h1[t1] = tanh(h0[t1] Wih1^T + h1[t1-1] Whh1^T + b)
    const int t1 = t - 1;
    const int s0 = t1 & 1;         // h0[t1] slot
    const int s1 = (t1 + 1) & 1;   // h1[t1-1] slot
    const float bv = bih1[jn] + bhh1[jn];
    f32x4 ac0 = {bv, bv, bv, bv};
    f32x4 ac1 = {0.f, 0.f, 0.f, 0.f};
    f32x4 ac2 = {0.f, 0.f, 0.f, 0.f};

    const u16t* p0h = ws + H0HI + (size_t)s0 * 65536 + (size_t)rowA * Hh + koff;
    const u16t* p0l = ws + H0LO + (size_t)s0 * 65536 + (size_t)rowA * Hh + koff;
#pragma unroll
    for (int kc = 0; kc < 16; ++kc) {
      F8 ah, al, bh, bl;
      ah.q = *(const uint4*)(p0h + kc * 32);
      al.q = *(const uint4*)(p0l + kc * 32);
      bh.q = *(const uint4*)(ws + WI1H + (size_t)jn * Hh + kc * 32 + koff);
      bl.q = *(const uint4*)(ws + WI1L + (size_t)jn * Hh + kc * 32 + koff);
      ac0 = MF(ah, bh, ac0);
      ac1 = MF(ah, bl, ac1);
      ac2 = MF(al, bh, ac2);
    }
    const u16t* p1h = ws + H1HI + (size_t)s1 * 65536 + (size_t)rowA * Hh + koff;
    const u16t* p1l = ws + H1LO + (size_t)s1 * 65536 + (size_t)rowA * Hh + koff;
#pragma unroll
    for (int kc = 0; kc < 16; ++kc) {
      F8 ah, al, bh, bl;
      ah.q = *(const uint4*)(p1h + kc * 32);
      al.q = *(const uint4*)(p1l + kc * 32);
      bh.q = *(const uint4*)(ws + WH1H + (size_t)jn * Hh + kc * 32 + koff);
      bl.q = *(const uint4*)(ws + WH1L + (size_t)jn * Hh + kc * 32 + koff);
      ac0 = MF(ah, bh, ac0);
      ac1 = MF(ah, bl, ac1);
      ac2 = MF(al, bh, ac2);
    }
    u16t* shi = ws + H1HI + (size_t)(t1 & 1) * 65536;
    u16t* slo = ws + H1LO + (size_t)(t1 & 1) * 65536;
#pragma unroll
    for (int r = 0; r < 4; ++r) {
      const float v = tanhf(ac0[r] + ac1[r] + ac2[r]);
      u16t hb, lb; splitRNE(v, hb, lb);
      const size_t m = (size_t)(mOutB + r) * Hh;
      shi[m + jn] = hb; slo[m + jn] = lb;
    }
  }
}

// ---- FC + softmax on h1[499] (slot 1). OUTPUT IS FLOAT32 (ref: f32 softmax).
__global__ __launch_bounds__(128) void fc_softmax(
    const u16t* __restrict__ ws, const float* __restrict__ Wfc,
    const float* __restrict__ bfc, float* __restrict__ out) {
  const int b = threadIdx.x;
  const int slot = (Tt - 1) & 1;   // 1
  const u16t* hh = ws + H1HI + (size_t)slot * 65536 + (size_t)b * Hh;
  const u16t* hl = ws + H1LO + (size_t)slot * 65536 + (size_t)b * Hh;
  float acc[4] = {bfc[0], bfc[1], bfc[2], bfc[3]};
  for (int j = 0; j < Hh; ++j) {
    const float hv = bf2f(hh[j]) + bf2f(hl[j]);
#pragma unroll
    for (int c = 0; c < 4; ++c) acc[c] += hv * Wfc[c * Hh + j];
  }
  const float mx = fmaxf(fmaxf(acc[0], acc[1]), fmaxf(acc[2], acc[3]));
  const float e0 = expf(acc[0] - mx), e1 = expf(acc[1] - mx);
  const float e2 = expf(acc[2] - mx), e3 = expf(acc[3] - mx);
  const float si = 1.f / (e0 + e1 + e2 + e3);
  out[b * 4 + 0] = e0 * si;
  out[b * 4 + 1] = e1 * si;
  out[b * 4 + 2] = e2 * si;
  out[b * 4 + 3] = e3 * si;
}

extern "C" void kernel_launch(void* const* d_in, const int* in_sizes, int n_in,
                              void* d_out, int out_size, void* d_ws, size_t ws_size,
                              hipStream_t stream) {
  const float* x    = (const float*)d_in[0];
  const float* Wih0 = (const float*)d_in[1];
  const float* Whh0 = (const float*)d_in[2];
  const float* bih0 = (const float*)d_in[3];
  const float* bhh0 = (const float*)d_in[4];
  const float* Wih1 = (const float*)d_in[5];
  const float* Whh1 = (const float*)d_in[6];
  const float* bih1 = (const float*)d_in[7];
  const float* bhh1 = (const float*)d_in[8];
  const float* Wfc  = (const float*)d_in[9];
  const float* bfc  = (const float*)d_in[10];
  float* out = (float*)d_out;            // reference output dtype: float32
  u16t* ws  = (u16t*)d_ws;

  // Weight hi/lo split + h-state zeroing (ws is poisoned 0xAA each call).
  wconv<<<dim3(5760), dim3(256), 0, stream>>>(Whh0, Wih0, Wih1, Whh1, ws);

  // 501 step launches; kernel boundaries are the global barriers.
  for (int t = 0; t <= Tt; ++t)
    rnn_step<<<dim3(128), dim3(256), 0, stream>>>(
        x, bih0, bhh0, bih1, bhh1, ws, t);

  fc_softmax<<<dim3(1), dim3(128), 0, stream>>>(ws, Wfc, bfc, out);
}